// Round 12
// baseline (171.574 us; speedup 1.0000x reference)
//
#include <hip/hip_runtime.h>
#include <hip/hip_bf16.h>

typedef unsigned short u16;
typedef unsigned int u32;
typedef __attribute__((ext_vector_type(8))) short short8;   // 8 bf16 = 4 VGPRs
typedef __attribute__((ext_vector_type(4))) float f32x4;    // MFMA C/D frag

#define LRELU_SLOPE 0.2f
#define EPS_LN 1e-5f
#define EPS_SM 1e-16f
#define NBLK 256          // edge chunks (binC' blocks)
#define CHMAX 4096        // max edges per chunk (E <= 1M)
#define CAP 4096          // fixed col capacity per bucket (~65 sigma above mean 1536)
// R12 = R7 VERBATIM re-bank (170.4us, passed). The LN1-in-GEMM fusion was
// abandoned after 4 consecutive failures (R8 crash, R9/R10 absmax, R11 crash);
// LN1 stays a separate block range in K1. One-pass chunk-local CSR: binC' sorts
// each edge-chunk by 128-dst bucket in LDS and writes ebuf CONTIGUOUSLY
// (chunk-major), exporting per-(bucket,chunk) offsets lpT/cntT — no global scan.
// binD' (per bucket) gathers its 256 mini-segments, builds the 128-dst sub-CSR,
// writes col into a fixed-capacity b*CAP region + rowse[d]=(start,deg).
// Pipeline (3 dispatches): ln1|binC' -> gemm|binD' -> agg.
// Requires n <= 65536 (src in 16 bits), NB <= 512, CH <= CHMAX, bucket load <= CAP.

__device__ __forceinline__ float bflo(u32 u){ union{u32 i; float f;} x; x.i = u<<16; return x.f; }
__device__ __forceinline__ float bfhi(u32 u){ union{u32 i; float f;} x; x.i = u & 0xffff0000u; return x.f; }
__device__ __forceinline__ float bf1(u16 u){ union{u32 i; float f;} x; x.i = ((u32)u)<<16; return x.f; }
__device__ __forceinline__ u16 f2bf(float f){
  union{float f; u32 i;} x; x.f=f; u32 i=x.i;
  u32 r = (i + 0x7fffu + ((i>>16)&1u))>>16; return (u16)r;
}
__device__ __forceinline__ u32 pack2(float a, float b){ return (u32)f2bf(a) | ((u32)f2bf(b)<<16); }
__device__ __forceinline__ float lrelu(float x){ return x > 0.f ? x : LRELU_SLOPE*x; }

__device__ __forceinline__ float wsum(float v){
  #pragma unroll
  for(int o=32;o>0;o>>=1) v += __shfl_xor(v,o,64);
  return v;
}

// exclusive scan of arr[0..m) in LDS by wave 0 (caller: if(tid<64) ...; barriers outside)
__device__ __forceinline__ void wave_excl_scan(int* arr, int m, int lane){
  int carry=0;
  for(int k0=0;k0<m;k0+=64){
    int idx=k0+lane;
    int v=(idx<m)? arr[idx]:0;
    int inc=v;
    #pragma unroll
    for(int o=1;o<64;o<<=1){ int t=__shfl_up(inc,o,64); if(lane>=o) inc+=t; }
    if(idx<m) arr[idx]=carry+inc-v;
    carry += __shfl(inc,63,64);
  }
}

// ---------------- K1: binC' (blocks < NBLK) | LN1 (remaining blocks) --------------
__global__ __launch_bounds__(256) void ln1C_kernel(const float* __restrict__ x,
    const float* __restrict__ g, const float* __restrict__ b,
    u16* __restrict__ xt, int n,
    const int* __restrict__ esrc, const int* __restrict__ edst,
    u32* __restrict__ ebuf, int* __restrict__ cntT, int* __restrict__ lpT,
    int E, int CH, int NB){
  __shared__ int cnt[512], cur[512];
  __shared__ u32 stage[CHMAX];
  int tid = threadIdx.x;

  if(blockIdx.x < NBLK){
    // ---- binC': chunk-local counting sort by bucket ----
    int i = blockIdx.x;
    for(int bb=tid; bb<NB; bb+=256) cnt[bb]=0;
    __syncthreads();
    int e0=i*CH, e1=min(E,e0+CH), cc=e1-e0;
    for(int k=tid;k<cc;k+=256) atomicAdd(&cnt[(u32)edst[e0+k]>>7],1);
    __syncthreads();
    for(int bb=tid; bb<NB; bb+=256) cntT[bb*NBLK+i]=cnt[bb];
    __syncthreads();                       // cnt reads done before in-place scan
    if(tid<64) wave_excl_scan(cnt,NB,tid);
    __syncthreads();
    for(int bb=tid; bb<NB; bb+=256){ int p=cnt[bb]; lpT[bb*NBLK+i]=p; cur[bb]=p; }
    __syncthreads();
    for(int k=tid;k<cc;k+=256){
      u32 s=(u32)esrc[e0+k], d=(u32)edst[e0+k];
      int p=atomicAdd(&cur[d>>7],1);
      stage[p] = s | ((d&127u)<<16);
    }
    __syncthreads();
    for(int k=tid;k<cc;k+=256) ebuf[(size_t)i*CH+k]=stage[k];   // coalesced
    return;
  }

  // ---- LN1 rows ----
  int row  = (int)(blockIdx.x - NBLK)*4 + (tid>>6);
  int lane = tid & 63;
  if(row >= n) return;
  float2 xv = ((const float2*)(x + (size_t)row*128))[lane];
  float v0 = xv.x, v1 = xv.y;
  float mean = wsum(v0+v1) * (1.f/128.f);
  float d0 = v0-mean, d1 = v1-mean;
  float var = wsum(d0*d0 + d1*d1) * (1.f/128.f);
  float rstd = rsqrtf(var + EPS_LN);
  float2 gv = ((const float2*)g)[lane], bv = ((const float2*)b)[lane];
  float o0 = d0*rstd*gv.x + bv.x;
  float o1 = d1*rstd*gv.y + bv.y;
  ((u32*)(xt + (size_t)row*128))[lane] = pack2(o0, o1);
}

// ---------------- K2: binD' (blocks < NB) | MFMA GEMM (remaining blocks) ----------
__global__ __launch_bounds__(256) void gemmD_kernel(const u16* __restrict__ xt,
    const float* __restrict__ W, const float* __restrict__ att_src, const float* __restrict__ att_dst,
    u16* __restrict__ h, float* __restrict__ a_src, float* __restrict__ a_dst, int n,
    const u32* __restrict__ ebuf, const int* __restrict__ cntT, const int* __restrict__ lpT,
    int2* __restrict__ rowse, u16* __restrict__ col, int NB, int CH){
  __shared__ __align__(16) char smem[50176];   // gemm: Wf(32KB)+Xb(17KB); binD': ~19KB
  int tid = threadIdx.x;

  if(blockIdx.x < (u32)NB){
    // ---- binD': per-bucket sub-CSR ----
    int bkt = blockIdx.x;
    int* segc = (int*)smem;                 // 256 ints
    int* dcnt = (int*)(smem+1024);          // 128 ints
    int* dcur = (int*)(smem+1536);          // 128 ints
    u32* list = (u32*)(smem+2048);          // CAP u32 (16KB)
    int c_i = cntT[bkt*NBLK+tid];           // this chunk's count for bucket bkt
    int l_i = lpT [bkt*NBLK+tid];           // local offset within chunk
    segc[tid] = c_i;
    if(tid<128) dcnt[tid]=0;
    __syncthreads();
    if(tid<64) wave_excl_scan(segc,256,tid);
    __syncthreads();
    int sb = segc[tid];
    int cb = segc[255] + cntT[bkt*NBLK+255];   // bucket total
    for(int k=0;k<c_i;k++) list[sb+k] = ebuf[(size_t)tid*CH + l_i + k];
    __syncthreads();
    for(int k=tid;k<cb;k+=256) atomicAdd(&dcnt[(list[k]>>16)&127], 1);
    __syncthreads();
    if(tid<64) wave_excl_scan(dcnt,128,tid);
    __syncthreads();
    int nd = min(128, n - (bkt<<7));
    if(tid<128){
      int st = dcnt[tid];
      int en = (tid<127)? dcnt[tid+1] : cb;
      dcur[tid] = st;
      if(tid<nd) rowse[(bkt<<7)+tid] = make_int2(bkt*CAP + st, en - st);
    }
    __syncthreads();
    for(int k=tid;k<cb;k+=256){
      u32 v = list[k]; int l = (int)((v>>16)&127u);
      int p = atomicAdd(&dcur[l], 1);
      col[bkt*CAP + p] = (u16)(v & 0xffffu);
    }
    return;
  }

  // ---- GEMM tile: h = xt @ W (bf16) + attention logits ----
  u16* Wf = (u16*)smem;            // 16384 u16, frag-major W
  u16* Xb = (u16*)(smem+32768);    // 64*136 u16 tile; reused for h staging
  int r0 = (int)(blockIdx.x - NB)*64;
  const float4* W4 = (const float4*)W;
  for(int p=tid; p<2048; p+=256){
    int gg = p & 31, kk = p >> 5;
    int k0 = kk*2, n0 = gg*4;
    float4 w0 = W4[k0*32 + gg];
    float4 w1 = W4[(k0+1)*32 + gg];
    int ks = k0>>5, q = (k0>>3)&3, j = k0&7;   // j even
    float e0[4] = {w0.x,w0.y,w0.z,w0.w};
    float e1[4] = {w1.x,w1.y,w1.z,w1.w};
    #pragma unroll
    for(int u=0;u<4;u++){
      int nn = n0+u;
      int idx = (((nn>>4)*4 + ks)*64 + q*16 + (nn&15))*8 + j;
      ((u32*)Wf)[idx>>1] = pack2(e0[u], e1[u]);
    }
  }
  for(int i=tid; i<1024; i+=256){
    int row = i>>4, seg = i&15;
    int gr = r0+row;
    uint4 v = (gr<n) ? ((const uint4*)(xt + (size_t)gr*128))[seg] : make_uint4(0,0,0,0);
    *(uint4*)&Xb[row*136 + seg*8] = v;
  }
  __syncthreads();

  int w = tid>>6, lane = tid&63;
  int slab = w*16, c = lane&15, q = lane>>4;
  f32x4 acc[8];
  #pragma unroll
  for(int t=0;t<8;t++) acc[t] = (f32x4){0.f,0.f,0.f,0.f};
  #pragma unroll
  for(int ks=0;ks<4;ks++){
    short8 A = *(const short8*)&Xb[(slab + c)*136 + ks*32 + q*8];
    #pragma unroll
    for(int t=0;t<8;t++){
      short8 B = *(const short8*)&Wf[((t*4+ks)*64 + lane)*8];
      acc[t] = __builtin_amdgcn_mfma_f32_16x16x32_bf16(A, B, acc[t], 0, 0, 0);
    }
  }
  __syncthreads();   // all waves done reading Xb
  #pragma unroll
  for(int t=0;t<8;t++){
    #pragma unroll
    for(int r=0;r<4;r++){
      Xb[(slab + q*4 + r)*136 + t*16 + c] = f2bf(acc[t][r]);   // C/D: col=lane&15, row=q*4+reg
    }
  }
  __syncthreads();
  {
    int row = tid>>2, qt = tid&3;
    int gr = r0+row;
    if(gr<n){
      const uint4* src = (const uint4*)((const char*)Xb + row*272 + qt*64);
      uint4* dst = (uint4*)((char*)(h + (size_t)gr*128) + qt*64);
      dst[0] = src[0];
      dst[1] = src[1];
      dst[2] = src[2];
      dst[3] = src[3];
    }
    int hd = qt;
    if(gr<n){
      float as=0.f, ad=0.f;
      const u16* hp = &Xb[row*136 + hd*32];
      #pragma unroll
      for(int sgm=0;sgm<4;sgm++){
        #pragma unroll
        for(int e=0;e<8;e++){
          float v = bf1(hp[sgm*8+e]);
          as = fmaf(v, att_src[hd*32+sgm*8+e], as);
          ad = fmaf(v, att_dst[hd*32+sgm*8+e], ad);
        }
      }
      a_src[(size_t)gr*4+hd] = as;
      a_dst[(size_t)gr*4+hd] = ad;
    }
  }
}

// ---------------- K3: Aggregation — softmax + gather + residual + LN2 -------------
// 16-lane group per dst, 4 dsts per wave, 3125 blocks. Lane li = 4*hc + eq owns
// channels li*8..li*8+7. y-pass: own head over 4 edges; gather: 2 shfl/edge
// (al, sj from lane gbase+4*hc+a, static element via unroll); denominator:
// 2 shfl_xor over eq bits. rowse[d] = (start, deg). No max-subtraction softmax.
__global__ __launch_bounds__(256) void agg_kernel(const u16* __restrict__ h,
    const float* __restrict__ a_src, const float* __restrict__ a_dst,
    const int2* __restrict__ rowse, const u16* __restrict__ col,
    const u16* __restrict__ xt, const float* __restrict__ bias,
    const float* __restrict__ g2, const float* __restrict__ b2,
    float* __restrict__ out, int n){
  int lane = threadIdx.x & 63;
  int wv   = threadIdx.x >> 6;
  int g    = lane >> 4;        // group within wave
  int li   = lane & 15;        // lane within group
  int hc   = li >> 2;          // head of this lane's 8 channels
  int eq   = li & 3;           // edge quad within chunk
  int gbase= g << 4;
  int d    = blockIdx.x*16 + wv*4 + g;
  bool dok = d < n;
  int dc   = dok ? d : (n-1);  // clamped: keep lanes alive for shfls

  float4 ad4v = ((const float4*)a_dst)[dc];
  float4 as4v = ((const float4*)a_src)[dc];
  float ad_h = hc==0? ad4v.x : hc==1? ad4v.y : hc==2? ad4v.z : ad4v.w;
  float as_h = hc==0? as4v.x : hc==1? as4v.y : hc==2? as4v.z : as4v.w;
  float t_h  = __expf(fminf(lrelu(as_h + ad_h), 60.f));   // self-loop term, own head

  int2 rs  = rowse[dc];
  int base = rs.x;
  int deg  = dok ? rs.y : 0;
  int dm = deg;                       // wave-uniform max degree over 4 groups
  dm = max(dm, __shfl_xor(dm, 16, 64));
  dm = max(dm, __shfl_xor(dm, 32, 64));

  float psum = 0.f;
  float acc[8]={};
  for(int j0=0;j0<dm;j0+=16){
    // ---- y-pass: own head, 4 edges (4*eq+c) ----
    int eb = j0 + eq*4;
    bool v0 = eb+0 < deg, v1 = eb+1 < deg, v2 = eb+2 < deg, v3 = eb+3 < deg;
    int sx0 = v0 ? (int)col[base+eb+0] : 0;
    int sx1 = v1 ? (int)col[base+eb+1] : 0;
    int sx2 = v2 ? (int)col[base+eb+2] : 0;
    int sx3 = v3 ? (int)col[base+eb+3] : 0;
    float y0 = v0 ? __expf(fminf(lrelu(a_src[sx0*4+hc]+ad_h),60.f)) : 0.f;
    float y1 = v1 ? __expf(fminf(lrelu(a_src[sx1*4+hc]+ad_h),60.f)) : 0.f;
    float y2 = v2 ? __expf(fminf(lrelu(a_src[sx2*4+hc]+ad_h),60.f)) : 0.f;
    float y3 = v3 ? __expf(fminf(lrelu(a_src[sx3*4+hc]+ad_h),60.f)) : 0.f;
    psum += (y0+y1) + (y2+y3);
    // ---- gather: 2 shfl per edge, static element index ----
    int ccm = min(deg - j0, 16);
    #pragma unroll 1
    for(int a=0; a<4; a++){
      int jb = a*4;
      if(jb >= ccm) break;                 // group-uniform
      int srcl = gbase + hc*4 + a;
      #define AGG_STEP(cc, yv, sv)                                              \
        if(jb + cc < ccm){                                                      \
          float al = __shfl(yv, srcl, 64);                                      \
          int   sj = __shfl(sv, srcl, 64);                                      \
          uint4 hv = *(const uint4*)(h + (size_t)sj*128 + li*8);                \
          acc[0]=fmaf(al,bflo(hv.x),acc[0]); acc[1]=fmaf(al,bfhi(hv.x),acc[1]); \
          acc[2]=fmaf(al,bflo(hv.y),acc[2]); acc[3]=fmaf(al,bfhi(hv.y),acc[3]); \
          acc[4]=fmaf(al,bflo(hv.z),acc[4]); acc[5]=fmaf(al,bfhi(hv.z),acc[5]); \
          acc[6]=fmaf(al,bflo(hv.w),acc[6]); acc[7]=fmaf(al,bfhi(hv.w),acc[7]); \
        }
      AGG_STEP(0, y0, sx0)
      AGG_STEP(1, y1, sx1)
      AGG_STEP(2, y2, sx2)
      AGG_STEP(3, y3, sx3)
      #undef AGG_STEP
    }
  }
  // denominator: reduce own-head partial across the 4 eq lanes of the quad
  psum += __shfl_xor(psum, 1, 64);
  psum += __shfl_xor(psum, 2, 64);
  float den = psum + t_h + EPS_SM;
  // self-loop message (each lane owns its channels)
  uint4 hd4 = *(const uint4*)(h + (size_t)dc*128 + li*8);
  acc[0]=fmaf(t_h,bflo(hd4.x),acc[0]); acc[1]=fmaf(t_h,bfhi(hd4.x),acc[1]);
  acc[2]=fmaf(t_h,bflo(hd4.y),acc[2]); acc[3]=fmaf(t_h,bfhi(hd4.y),acc[3]);
  acc[4]=fmaf(t_h,bflo(hd4.z),acc[4]); acc[5]=fmaf(t_h,bfhi(hd4.z),acc[5]);
  acc[6]=fmaf(t_h,bflo(hd4.w),acc[6]); acc[7]=fmaf(t_h,bfhi(hd4.w),acc[7]);
  float inv = 1.f/den;

  // bias + residual (bf16 xt) + LN2 (each channel once over 16 lanes -> /128)
  uint4 xv4 = *(const uint4*)(xt + (size_t)dc*128 + li*8);
  const float* bp = bias + li*8;
  float4 ba = *(const float4*)bp, bb = *(const float4*)(bp+4);
  float r[8];
  r[0]=bflo(xv4.x)+acc[0]*inv+ba.x; r[1]=bfhi(xv4.x)+acc[1]*inv+ba.y;
  r[2]=bflo(xv4.y)+acc[2]*inv+ba.z; r[3]=bfhi(xv4.y)+acc[3]*inv+ba.w;
  r[4]=bflo(xv4.z)+acc[4]*inv+bb.x; r[5]=bfhi(xv4.z)+acc[5]*inv+bb.y;
  r[6]=bflo(xv4.w)+acc[6]*inv+bb.z; r[7]=bfhi(xv4.w)+acc[7]*inv+bb.w;
  float part=0;
  #pragma unroll
  for(int c2=0;c2<8;c2++) part+=r[c2];
  #pragma unroll
  for(int o=1;o<16;o<<=1) part += __shfl_xor(part,o,64);
  float mean = part*(1.f/128.f);
  float vp=0;
  #pragma unroll
  for(int c2=0;c2<8;c2++){ float dd=r[c2]-mean; vp+=dd*dd; }
  #pragma unroll
  for(int o=1;o<16;o<<=1) vp += __shfl_xor(vp,o,64);
  float var = vp*(1.f/128.f);
  float rstd = rsqrtf(var+EPS_LN);
  const float* gp = g2 + li*8; const float* b2p = b2 + li*8;
  float4 ga = *(const float4*)gp,  gb = *(const float4*)(gp+4);
  float4 c2a= *(const float4*)b2p, c2b= *(const float4*)(b2p+4);
  if(dok){
    float* op = out + (size_t)d*128 + li*8;
    float4 o0 = make_float4((r[0]-mean)*rstd*ga.x+c2a.x, (r[1]-mean)*rstd*ga.y+c2a.y,
                            (r[2]-mean)*rstd*ga.z+c2a.z, (r[3]-mean)*rstd*ga.w+c2a.w);
    float4 o1 = make_float4((r[4]-mean)*rstd*gb.x+c2b.x, (r[5]-mean)*rstd*gb.y+c2b.y,
                            (r[6]-mean)*rstd*gb.z+c2b.z, (r[7]-mean)*rstd*gb.w+c2b.w);
    *(float4*)op     = o0;
    *(float4*)(op+4) = o1;
  }
}

extern "C" void kernel_launch(void* const* d_in, const int* in_sizes, int n_in,
                              void* d_out, int out_size, void* d_ws, size_t ws_size,
                              hipStream_t stream) {
  const float* x     = (const float*)d_in[0];
  const int*   ei    = (const int*)d_in[1];
  const float* W     = (const float*)d_in[4];
  const float* att_s = (const float*)d_in[5];
  const float* att_d = (const float*)d_in[6];
  const float* bias  = (const float*)d_in[7];
  const float* g1    = (const float*)d_in[8];
  const float* b1    = (const float*)d_in[9];
  const float* g2    = (const float*)d_in[10];
  const float* b2    = (const float*)d_in[11];
  int n = in_sizes[0]/128;
  int E = in_sizes[1]/2;
  float* out = (float*)d_out;

  int NB = (n+127)>>7;                 // 128-dst buckets (391 for n=50000)
  int CH = (E + NBLK - 1)/NBLK;        // edges per chunk (2344), <= CHMAX

  char* ws = (char*)d_ws;              // ~34 MB of 256 MiB used
  u16*   xt    = (u16*)ws;   ws += (size_t)n*128*2;
  u16*   h     = (u16*)ws;   ws += (size_t)n*128*2;
  float* a_src = (float*)ws; ws += (size_t)n*4*4;
  float* a_dst = (float*)ws; ws += (size_t)n*4*4;
  int2*  rowse = (int2*)ws;  ws += (size_t)n*8;
  u16*   col   = (u16*)ws;   ws += (size_t)NB*CAP*2;
  u32*   ebuf  = (u32*)ws;   ws += (size_t)NBLK*CH*4;
  int*   cntT  = (int*)ws;   ws += (size_t)NB*NBLK*4;
  int*   lpT   = (int*)ws;   ws += (size_t)NB*NBLK*4;

  int gemmTiles = (n+63)/64;
  dim3 b256(256);
  ln1C_kernel <<<NBLK + (n+3)/4,  b256, 0, stream>>>(x, g1, b1, xt, n,
                                                     ei, ei+E, ebuf, cntT, lpT, E, CH, NB);
  gemmD_kernel<<<NB + gemmTiles,  b256, 0, stream>>>(xt, W, att_s, att_d, h, a_src, a_dst, n,
                                                     ebuf, cntT, lpT, rowse, col, NB, CH);
  agg_kernel  <<<(n+15)/16,       b256, 0, stream>>>(h, a_src, a_dst, rowse, col,
                                                     xt, bias, g2, b2, out, n);
}

// Round 13
// 166.886 us; speedup vs baseline: 1.0281x; 1.0281x over previous
//
#include <hip/hip_runtime.h>
#include <hip/hip_bf16.h>

typedef unsigned short u16;
typedef unsigned int u32;
typedef __attribute__((ext_vector_type(8))) short short8;   // 8 bf16 = 4 VGPRs
typedef __attribute__((ext_vector_type(4))) float f32x4;    // MFMA C/D frag

#define LRELU_SLOPE 0.2f
#define EPS_LN 1e-5f
#define EPS_SM 1e-16f
#define NBLK 256          // edge chunks (binC' blocks)
#define CHMAX 4096        // max edges per chunk (E <= 1M)
#define CAP 4096          // fixed col capacity per bucket (~65 sigma above mean 1536)
// R13 = R12 (proven, 171.6us) + two conservative micro-opts:
//  (1) agg gather: ONE shfl/edge — y-pass packs (bf16(y) << 16 | sx) so the
//      broadcast carries both alpha and src id in a single u32 (al = bfhi(v)).
//  (2) W pre-converted to frag-major bf16 ONCE (extra block in K1 -> Wfg 32KB);
//      GEMM blocks stage Wf with plain uint4 copies (no per-block repack).
// Pipeline (3 dispatches): ln1|Wstage|binC' -> gemm|binD' -> agg.
// Requires n <= 65536 (src in 16 bits), NB <= 512, CH <= CHMAX, bucket load <= CAP.

__device__ __forceinline__ float bflo(u32 u){ union{u32 i; float f;} x; x.i = u<<16; return x.f; }
__device__ __forceinline__ float bfhi(u32 u){ union{u32 i; float f;} x; x.i = u & 0xffff0000u; return x.f; }
__device__ __forceinline__ float bf1(u16 u){ union{u32 i; float f;} x; x.i = ((u32)u)<<16; return x.f; }
__device__ __forceinline__ u16 f2bf(float f){
  union{float f; u32 i;} x; x.f=f; u32 i=x.i;
  u32 r = (i + 0x7fffu + ((i>>16)&1u))>>16; return (u16)r;
}
__device__ __forceinline__ u32 pack2(float a, float b){ return (u32)f2bf(a) | ((u32)f2bf(b)<<16); }
__device__ __forceinline__ float lrelu(float x){ return x > 0.f ? x : LRELU_SLOPE*x; }

__device__ __forceinline__ float wsum(float v){
  #pragma unroll
  for(int o=32;o>0;o>>=1) v += __shfl_xor(v,o,64);
  return v;
}

// exclusive scan of arr[0..m) in LDS by wave 0 (caller: if(tid<64) ...; barriers outside)
__device__ __forceinline__ void wave_excl_scan(int* arr, int m, int lane){
  int carry=0;
  for(int k0=0;k0<m;k0+=64){
    int idx=k0+lane;
    int v=(idx<m)? arr[idx]:0;
    int inc=v;
    #pragma unroll
    for(int o=1;o<64;o<<=1){ int t=__shfl_up(inc,o,64); if(lane>=o) inc+=t; }
    if(idx<m) arr[idx]=carry+inc-v;
    carry += __shfl(inc,63,64);
  }
}

// ------- K1: binC' (blocks < NBLK) | W pre-stage (block NBLK) | LN1 (rest) --------
__global__ __launch_bounds__(256) void ln1C_kernel(const float* __restrict__ x,
    const float* __restrict__ g, const float* __restrict__ b,
    u16* __restrict__ xt, int n,
    const int* __restrict__ esrc, const int* __restrict__ edst,
    u32* __restrict__ ebuf, int* __restrict__ cntT, int* __restrict__ lpT,
    const float* __restrict__ W, u16* __restrict__ Wfg,
    int E, int CH, int NB){
  __shared__ int cnt[512], cur[512];
  __shared__ u32 stage[CHMAX];
  int tid = threadIdx.x;

  if(blockIdx.x < NBLK){
    // ---- binC': chunk-local counting sort by bucket ----
    int i = blockIdx.x;
    for(int bb=tid; bb<NB; bb+=256) cnt[bb]=0;
    __syncthreads();
    int e0=i*CH, e1=min(E,e0+CH), cc=e1-e0;
    for(int k=tid;k<cc;k+=256) atomicAdd(&cnt[(u32)edst[e0+k]>>7],1);
    __syncthreads();
    for(int bb=tid; bb<NB; bb+=256) cntT[bb*NBLK+i]=cnt[bb];
    __syncthreads();                       // cnt reads done before in-place scan
    if(tid<64) wave_excl_scan(cnt,NB,tid);
    __syncthreads();
    for(int bb=tid; bb<NB; bb+=256){ int p=cnt[bb]; lpT[bb*NBLK+i]=p; cur[bb]=p; }
    __syncthreads();
    for(int k=tid;k<cc;k+=256){
      u32 s=(u32)esrc[e0+k], d=(u32)edst[e0+k];
      int p=atomicAdd(&cur[d>>7],1);
      stage[p] = s | ((d&127u)<<16);
    }
    __syncthreads();
    for(int k=tid;k<cc;k+=256) ebuf[(size_t)i*CH+k]=stage[k];   // coalesced
    return;
  }

  if(blockIdx.x == NBLK){
    // ---- W pre-stage: frag-major bf16 Wfg (32KB), done once ----
    // element W[k][nn] at u16 idx (((nn>>4)*4 + ks)*64 + q*16 + (nn&15))*8 + j
    const float4* W4 = (const float4*)W;
    for(int p=tid; p<2048; p+=256){
      int gg = p & 31, kk = p >> 5;
      int k0 = kk*2, n0 = gg*4;
      float4 w0 = W4[k0*32 + gg];
      float4 w1 = W4[(k0+1)*32 + gg];
      int ks = k0>>5, q = (k0>>3)&3, j = k0&7;   // j even
      float e0[4] = {w0.x,w0.y,w0.z,w0.w};
      float e1[4] = {w1.x,w1.y,w1.z,w1.w};
      #pragma unroll
      for(int u=0;u<4;u++){
        int nn = n0+u;
        int idx = (((nn>>4)*4 + ks)*64 + q*16 + (nn&15))*8 + j;
        ((u32*)Wfg)[idx>>1] = pack2(e0[u], e1[u]);
      }
    }
    return;
  }

  // ---- LN1 rows ----
  int row  = (int)(blockIdx.x - NBLK - 1)*4 + (tid>>6);
  int lane = tid & 63;
  if(row >= n) return;
  float2 xv = ((const float2*)(x + (size_t)row*128))[lane];
  float v0 = xv.x, v1 = xv.y;
  float mean = wsum(v0+v1) * (1.f/128.f);
  float d0 = v0-mean, d1 = v1-mean;
  float var = wsum(d0*d0 + d1*d1) * (1.f/128.f);
  float rstd = rsqrtf(var + EPS_LN);
  float2 gv = ((const float2*)g)[lane], bv = ((const float2*)b)[lane];
  float o0 = d0*rstd*gv.x + bv.x;
  float o1 = d1*rstd*gv.y + bv.y;
  ((u32*)(xt + (size_t)row*128))[lane] = pack2(o0, o1);
}

// ---------------- K2: binD' (blocks < NB) | MFMA GEMM (remaining blocks) ----------
__global__ __launch_bounds__(256) void gemmD_kernel(const u16* __restrict__ xt,
    const u16* __restrict__ Wfg, const float* __restrict__ att_src, const float* __restrict__ att_dst,
    u16* __restrict__ h, float* __restrict__ a_src, float* __restrict__ a_dst, int n,
    const u32* __restrict__ ebuf, const int* __restrict__ cntT, const int* __restrict__ lpT,
    int2* __restrict__ rowse, u16* __restrict__ col, int NB, int CH){
  __shared__ __align__(16) char smem[50176];   // gemm: Wf(32KB)+Xb(17KB); binD': ~19KB
  int tid = threadIdx.x;

  if(blockIdx.x < (u32)NB){
    // ---- binD': per-bucket sub-CSR ----
    int bkt = blockIdx.x;
    int* segc = (int*)smem;                 // 256 ints
    int* dcnt = (int*)(smem+1024);          // 128 ints
    int* dcur = (int*)(smem+1536);          // 128 ints
    u32* list = (u32*)(smem+2048);          // CAP u32 (16KB)
    int c_i = cntT[bkt*NBLK+tid];           // this chunk's count for bucket bkt
    int l_i = lpT [bkt*NBLK+tid];           // local offset within chunk
    segc[tid] = c_i;
    if(tid<128) dcnt[tid]=0;
    __syncthreads();
    if(tid<64) wave_excl_scan(segc,256,tid);
    __syncthreads();
    int sb = segc[tid];
    int cb = segc[255] + cntT[bkt*NBLK+255];   // bucket total
    for(int k=0;k<c_i;k++) list[sb+k] = ebuf[(size_t)tid*CH + l_i + k];
    __syncthreads();
    for(int k=tid;k<cb;k+=256) atomicAdd(&dcnt[(list[k]>>16)&127], 1);
    __syncthreads();
    if(tid<64) wave_excl_scan(dcnt,128,tid);
    __syncthreads();
    int nd = min(128, n - (bkt<<7));
    if(tid<128){
      int st = dcnt[tid];
      int en = (tid<127)? dcnt[tid+1] : cb;
      dcur[tid] = st;
      if(tid<nd) rowse[(bkt<<7)+tid] = make_int2(bkt*CAP + st, en - st);
    }
    __syncthreads();
    for(int k=tid;k<cb;k+=256){
      u32 v = list[k]; int l = (int)((v>>16)&127u);
      int p = atomicAdd(&dcur[l], 1);
      col[bkt*CAP + p] = (u16)(v & 0xffffu);
    }
    return;
  }

  // ---- GEMM tile: h = xt @ W (bf16) + attention logits ----
  u16* Wf = (u16*)smem;            // 16384 u16, frag-major W
  u16* Xb = (u16*)(smem+32768);    // 64*136 u16 tile; reused for h staging
  int r0 = (int)(blockIdx.x - NB)*64;
  // stage pre-converted W (plain copies: 2048 uint4, 8 per thread)
  {
    const uint4* Wg4 = (const uint4*)Wfg;
    uint4* Wf4 = (uint4*)Wf;
    for(int p=tid; p<2048; p+=256) Wf4[p] = Wg4[p];
  }
  for(int i=tid; i<1024; i+=256){
    int row = i>>4, seg = i&15;
    int gr = r0+row;
    uint4 v = (gr<n) ? ((const uint4*)(xt + (size_t)gr*128))[seg] : make_uint4(0,0,0,0);
    *(uint4*)&Xb[row*136 + seg*8] = v;
  }
  __syncthreads();

  int w = tid>>6, lane = tid&63;
  int slab = w*16, c = lane&15, q = lane>>4;
  f32x4 acc[8];
  #pragma unroll
  for(int t=0;t<8;t++) acc[t] = (f32x4){0.f,0.f,0.f,0.f};
  #pragma unroll
  for(int ks=0;ks<4;ks++){
    short8 A = *(const short8*)&Xb[(slab + c)*136 + ks*32 + q*8];
    #pragma unroll
    for(int t=0;t<8;t++){
      short8 B = *(const short8*)&Wf[((t*4+ks)*64 + lane)*8];
      acc[t] = __builtin_amdgcn_mfma_f32_16x16x32_bf16(A, B, acc[t], 0, 0, 0);
    }
  }
  __syncthreads();   // all waves done reading Xb
  #pragma unroll
  for(int t=0;t<8;t++){
    #pragma unroll
    for(int r=0;r<4;r++){
      Xb[(slab + q*4 + r)*136 + t*16 + c] = f2bf(acc[t][r]);   // C/D: col=lane&15, row=q*4+reg
    }
  }
  __syncthreads();
  {
    int row = tid>>2, qt = tid&3;
    int gr = r0+row;
    if(gr<n){
      const uint4* src = (const uint4*)((const char*)Xb + row*272 + qt*64);
      uint4* dst = (uint4*)((char*)(h + (size_t)gr*128) + qt*64);
      dst[0] = src[0];
      dst[1] = src[1];
      dst[2] = src[2];
      dst[3] = src[3];
    }
    int hd = qt;
    if(gr<n){
      float as=0.f, ad=0.f;
      const u16* hp = &Xb[row*136 + hd*32];
      #pragma unroll
      for(int sgm=0;sgm<4;sgm++){
        #pragma unroll
        for(int e=0;e<8;e++){
          float v = bf1(hp[sgm*8+e]);
          as = fmaf(v, att_src[hd*32+sgm*8+e], as);
          ad = fmaf(v, att_dst[hd*32+sgm*8+e], ad);
        }
      }
      a_src[(size_t)gr*4+hd] = as;
      a_dst[(size_t)gr*4+hd] = ad;
    }
  }
}

// ---------------- K3: Aggregation — softmax + gather + residual + LN2 -------------
// 16-lane group per dst, 4 dsts per wave, 3125 blocks. Lane li = 4*hc + eq owns
// channels li*8..li*8+7. y-pass: own head over 4 edges, packing (bf16(y)<<16|sx)
// so the gather needs ONE shfl/edge: al = bfhi(v) (bf16 alpha, bounded rounding),
// sj = v & 0xffff. Denominator stays f32 (2 shfl_xor over eq bits).
// rowse[d] = (start, deg). No max-subtraction softmax (logits small; clamp 60).
__global__ __launch_bounds__(256) void agg_kernel(const u16* __restrict__ h,
    const float* __restrict__ a_src, const float* __restrict__ a_dst,
    const int2* __restrict__ rowse, const u16* __restrict__ col,
    const u16* __restrict__ xt, const float* __restrict__ bias,
    const float* __restrict__ g2, const float* __restrict__ b2,
    float* __restrict__ out, int n){
  int lane = threadIdx.x & 63;
  int wv   = threadIdx.x >> 6;
  int g    = lane >> 4;        // group within wave
  int li   = lane & 15;        // lane within group
  int hc   = li >> 2;          // head of this lane's 8 channels
  int eq   = li & 3;           // edge quad within chunk
  int gbase= g << 4;
  int d    = blockIdx.x*16 + wv*4 + g;
  bool dok = d < n;
  int dc   = dok ? d : (n-1);  // clamped: keep lanes alive for shfls

  float4 ad4v = ((const float4*)a_dst)[dc];
  float4 as4v = ((const float4*)a_src)[dc];
  float ad_h = hc==0? ad4v.x : hc==1? ad4v.y : hc==2? ad4v.z : ad4v.w;
  float as_h = hc==0? as4v.x : hc==1? as4v.y : hc==2? as4v.z : as4v.w;
  float t_h  = __expf(fminf(lrelu(as_h + ad_h), 60.f));   // self-loop term, own head

  int2 rs  = rowse[dc];
  int base = rs.x;
  int deg  = dok ? rs.y : 0;
  int dm = deg;                       // wave-uniform max degree over 4 groups
  dm = max(dm, __shfl_xor(dm, 16, 64));
  dm = max(dm, __shfl_xor(dm, 32, 64));

  float psum = 0.f;
  float acc[8]={};
  for(int j0=0;j0<dm;j0+=16){
    // ---- y-pass: own head, 4 edges (4*eq+c); pack (bf16(y), sx) ----
    int eb = j0 + eq*4;
    bool v0 = eb+0 < deg, v1 = eb+1 < deg, v2 = eb+2 < deg, v3 = eb+3 < deg;
    int sx0 = v0 ? (int)col[base+eb+0] : 0;
    int sx1 = v1 ? (int)col[base+eb+1] : 0;
    int sx2 = v2 ? (int)col[base+eb+2] : 0;
    int sx3 = v3 ? (int)col[base+eb+3] : 0;
    float y0 = v0 ? __expf(fminf(lrelu(a_src[sx0*4+hc]+ad_h),60.f)) : 0.f;
    float y1 = v1 ? __expf(fminf(lrelu(a_src[sx1*4+hc]+ad_h),60.f)) : 0.f;
    float y2 = v2 ? __expf(fminf(lrelu(a_src[sx2*4+hc]+ad_h),60.f)) : 0.f;
    float y3 = v3 ? __expf(fminf(lrelu(a_src[sx3*4+hc]+ad_h),60.f)) : 0.f;
    psum += (y0+y1) + (y2+y3);
    int pk0 = (int)(((u32)f2bf(y0)<<16) | (u32)sx0);
    int pk1 = (int)(((u32)f2bf(y1)<<16) | (u32)sx1);
    int pk2 = (int)(((u32)f2bf(y2)<<16) | (u32)sx2);
    int pk3 = (int)(((u32)f2bf(y3)<<16) | (u32)sx3);
    // ---- gather: ONE shfl per edge (al=bfhi(v), sj=v&0xffff) ----
    int ccm = min(deg - j0, 16);
    #pragma unroll 1
    for(int a=0; a<4; a++){
      int jb = a*4;
      if(jb >= ccm) break;                 // group-uniform
      int srcl = gbase + hc*4 + a;
      #define AGG_STEP(cc, pv)                                                  \
        if(jb + cc < ccm){                                                      \
          u32 v = (u32)__shfl(pv, srcl, 64);                                    \
          float al = bfhi(v);                                                   \
          int   sj = (int)(v & 0xffffu);                                        \
          uint4 hv = *(const uint4*)(h + (size_t)sj*128 + li*8);                \
          acc[0]=fmaf(al,bflo(hv.x),acc[0]); acc[1]=fmaf(al,bfhi(hv.x),acc[1]); \
          acc[2]=fmaf(al,bflo(hv.y),acc[2]); acc[3]=fmaf(al,bfhi(hv.y),acc[3]); \
          acc[4]=fmaf(al,bflo(hv.z),acc[4]); acc[5]=fmaf(al,bfhi(hv.z),acc[5]); \
          acc[6]=fmaf(al,bflo(hv.w),acc[6]); acc[7]=fmaf(al,bfhi(hv.w),acc[7]); \
        }
      AGG_STEP(0, pk0)
      AGG_STEP(1, pk1)
      AGG_STEP(2, pk2)
      AGG_STEP(3, pk3)
      #undef AGG_STEP
    }
  }
  // denominator: reduce own-head partial across the 4 eq lanes of the quad
  psum += __shfl_xor(psum, 1, 64);
  psum += __shfl_xor(psum, 2, 64);
  float den = psum + t_h + EPS_SM;
  // self-loop message (each lane owns its channels)
  uint4 hd4 = *(const uint4*)(h + (size_t)dc*128 + li*8);
  acc[0]=fmaf(t_h,bflo(hd4.x),acc[0]); acc[1]=fmaf(t_h,bfhi(hd4.x),acc[1]);
  acc[2]=fmaf(t_h,bflo(hd4.y),acc[2]); acc[3]=fmaf(t_h,bfhi(hd4.y),acc[3]);
  acc[4]=fmaf(t_h,bflo(hd4.z),acc[4]); acc[5]=fmaf(t_h,bfhi(hd4.z),acc[5]);
  acc[6]=fmaf(t_h,bflo(hd4.w),acc[6]); acc[7]=fmaf(t_h,bfhi(hd4.w),acc[7]);
  float inv = 1.f/den;

  // bias + residual (bf16 xt) + LN2 (each channel once over 16 lanes -> /128)
  uint4 xv4 = *(const uint4*)(xt + (size_t)dc*128 + li*8);
  const float* bp = bias + li*8;
  float4 ba = *(const float4*)bp, bb = *(const float4*)(bp+4);
  float r[8];
  r[0]=bflo(xv4.x)+acc[0]*inv+ba.x; r[1]=bfhi(xv4.x)+acc[1]*inv+ba.y;
  r[2]=bflo(xv4.y)+acc[2]*inv+ba.z; r[3]=bfhi(xv4.y)+acc[3]*inv+ba.w;
  r[4]=bflo(xv4.z)+acc[4]*inv+bb.x; r[5]=bfhi(xv4.z)+acc[5]*inv+bb.y;
  r[6]=bflo(xv4.w)+acc[6]*inv+bb.z; r[7]=bfhi(xv4.w)+acc[7]*inv+bb.w;
  float part=0;
  #pragma unroll
  for(int c2=0;c2<8;c2++) part+=r[c2];
  #pragma unroll
  for(int o=1;o<16;o<<=1) part += __shfl_xor(part,o,64);
  float mean = part*(1.f/128.f);
  float vp=0;
  #pragma unroll
  for(int c2=0;c2<8;c2++){ float dd=r[c2]-mean; vp+=dd*dd; }
  #pragma unroll
  for(int o=1;o<16;o<<=1) vp += __shfl_xor(vp,o,64);
  float var = vp*(1.f/128.f);
  float rstd = rsqrtf(var+EPS_LN);
  const float* gp = g2 + li*8; const float* b2p = b2 + li*8;
  float4 ga = *(const float4*)gp,  gb = *(const float4*)(gp+4);
  float4 c2a= *(const float4*)b2p, c2b= *(const float4*)(b2p+4);
  if(dok){
    float* op = out + (size_t)d*128 + li*8;
    float4 o0 = make_float4((r[0]-mean)*rstd*ga.x+c2a.x, (r[1]-mean)*rstd*ga.y+c2a.y,
                            (r[2]-mean)*rstd*ga.z+c2a.z, (r[3]-mean)*rstd*ga.w+c2a.w);
    float4 o1 = make_float4((r[4]-mean)*rstd*gb.x+c2b.x, (r[5]-mean)*rstd*gb.y+c2b.y,
                            (r[6]-mean)*rstd*gb.z+c2b.z, (r[7]-mean)*rstd*gb.w+c2b.w);
    *(float4*)op     = o0;
    *(float4*)(op+4) = o1;
  }
}

extern "C" void kernel_launch(void* const* d_in, const int* in_sizes, int n_in,
                              void* d_out, int out_size, void* d_ws, size_t ws_size,
                              hipStream_t stream) {
  const float* x     = (const float*)d_in[0];
  const int*   ei    = (const int*)d_in[1];
  const float* W     = (const float*)d_in[4];
  const float* att_s = (const float*)d_in[5];
  const float* att_d = (const float*)d_in[6];
  const float* bias  = (const float*)d_in[7];
  const float* g1    = (const float*)d_in[8];
  const float* b1    = (const float*)d_in[9];
  const float* g2    = (const float*)d_in[10];
  const float* b2    = (const float*)d_in[11];
  int n = in_sizes[0]/128;
  int E = in_sizes[1]/2;
  float* out = (float*)d_out;

  int NB = (n+127)>>7;                 // 128-dst buckets (391 for n=50000)
  int CH = (E + NBLK - 1)/NBLK;        // edges per chunk (2344), <= CHMAX

  char* ws = (char*)d_ws;              // ~34 MB of 256 MiB used
  u16*   xt    = (u16*)ws;   ws += (size_t)n*128*2;
  u16*   h     = (u16*)ws;   ws += (size_t)n*128*2;
  float* a_src = (float*)ws; ws += (size_t)n*4*4;
  float* a_dst = (float*)ws; ws += (size_t)n*4*4;
  int2*  rowse = (int2*)ws;  ws += (size_t)n*8;
  u16*   col   = (u16*)ws;   ws += (size_t)NB*CAP*2;
  u32*   ebuf  = (u32*)ws;   ws += (size_t)NBLK*CH*4;
  int*   cntT  = (int*)ws;   ws += (size_t)NB*NBLK*4;
  int*   lpT   = (int*)ws;   ws += (size_t)NB*NBLK*4;
  u16*   Wfg   = (u16*)ws;   ws += 16384*2;   // frag-major bf16 W (32KB)

  int gemmTiles = (n+63)/64;
  dim3 b256(256);
  ln1C_kernel <<<NBLK + 1 + (n+3)/4, b256, 0, stream>>>(x, g1, b1, xt, n,
                                                        ei, ei+E, ebuf, cntT, lpT,
                                                        W, Wfg, E, CH, NB);
  gemmD_kernel<<<NB + gemmTiles,     b256, 0, stream>>>(xt, Wfg, att_s, att_d, h, a_src, a_dst, n,
                                                        ebuf, cntT, lpT, rowse, col, NB, CH);
  agg_kernel  <<<(n+15)/16,          b256, 0, stream>>>(h, a_src, a_dst, rowse, col,
                                                        xt, bias, g2, b2, out, n);
}

// Round 14
// 164.511 us; speedup vs baseline: 1.0429x; 1.0144x over previous
//
#include <hip/hip_runtime.h>
#include <hip/hip_bf16.h>

typedef unsigned short u16;
typedef unsigned int u32;
typedef __attribute__((ext_vector_type(8))) short short8;   // 8 bf16 = 4 VGPRs
typedef __attribute__((ext_vector_type(4))) float f32x4;    // MFMA C/D frag

#define LRELU_SLOPE 0.2f
#define EPS_LN 1e-5f
#define EPS_SM 1e-16f
#define NBLK 256          // edge chunks (binC' blocks)
#define CHMAX 4096        // max edges per chunk (E <= 1M)
#define CAP 4096          // fixed col capacity per bucket (mean 1536+pad<=1920, ~57 sigma headroom)
// R14 = R13 (166.9us) + aligned col segments: binD' pads each dst's col start to
// a multiple of 4 u16 (scan padded counts), so agg loads 4 edge ids as ONE
// guarded uint2 instead of 4 scalar u16 loads (in-segment by construction:
// eb<deg, eb%4==0 => eb+3 < padded segment size).
// Pipeline (3 dispatches): ln1|Wstage|binC' -> gemm|binD' -> agg.
// Requires n <= 65536 (src in 16 bits), NB <= 512, CH <= CHMAX, bucket load+pad <= CAP.

__device__ __forceinline__ float bflo(u32 u){ union{u32 i; float f;} x; x.i = u<<16; return x.f; }
__device__ __forceinline__ float bfhi(u32 u){ union{u32 i; float f;} x; x.i = u & 0xffff0000u; return x.f; }
__device__ __forceinline__ float bf1(u16 u){ union{u32 i; float f;} x; x.i = ((u32)u)<<16; return x.f; }
__device__ __forceinline__ u16 f2bf(float f){
  union{float f; u32 i;} x; x.f=f; u32 i=x.i;
  u32 r = (i + 0x7fffu + ((i>>16)&1u))>>16; return (u16)r;
}
__device__ __forceinline__ u32 pack2(float a, float b){ return (u32)f2bf(a) | ((u32)f2bf(b)<<16); }
__device__ __forceinline__ float lrelu(float x){ return x > 0.f ? x : LRELU_SLOPE*x; }

__device__ __forceinline__ float wsum(float v){
  #pragma unroll
  for(int o=32;o>0;o>>=1) v += __shfl_xor(v,o,64);
  return v;
}

// exclusive scan of arr[0..m) in LDS by wave 0 (caller: if(tid<64) ...; barriers outside)
__device__ __forceinline__ void wave_excl_scan(int* arr, int m, int lane){
  int carry=0;
  for(int k0=0;k0<m;k0+=64){
    int idx=k0+lane;
    int v=(idx<m)? arr[idx]:0;
    int inc=v;
    #pragma unroll
    for(int o=1;o<64;o<<=1){ int t=__shfl_up(inc,o,64); if(lane>=o) inc+=t; }
    if(idx<m) arr[idx]=carry+inc-v;
    carry += __shfl(inc,63,64);
  }
}

// ------- K1: binC' (blocks < NBLK) | W pre-stage (block NBLK) | LN1 (rest) --------
__global__ __launch_bounds__(256) void ln1C_kernel(const float* __restrict__ x,
    const float* __restrict__ g, const float* __restrict__ b,
    u16* __restrict__ xt, int n,
    const int* __restrict__ esrc, const int* __restrict__ edst,
    u32* __restrict__ ebuf, int* __restrict__ cntT, int* __restrict__ lpT,
    const float* __restrict__ W, u16* __restrict__ Wfg,
    int E, int CH, int NB){
  __shared__ int cnt[512], cur[512];
  __shared__ u32 stage[CHMAX];
  int tid = threadIdx.x;

  if(blockIdx.x < NBLK){
    // ---- binC': chunk-local counting sort by bucket ----
    int i = blockIdx.x;
    for(int bb=tid; bb<NB; bb+=256) cnt[bb]=0;
    __syncthreads();
    int e0=i*CH, e1=min(E,e0+CH), cc=e1-e0;
    for(int k=tid;k<cc;k+=256) atomicAdd(&cnt[(u32)edst[e0+k]>>7],1);
    __syncthreads();
    for(int bb=tid; bb<NB; bb+=256) cntT[bb*NBLK+i]=cnt[bb];
    __syncthreads();                       // cnt reads done before in-place scan
    if(tid<64) wave_excl_scan(cnt,NB,tid);
    __syncthreads();
    for(int bb=tid; bb<NB; bb+=256){ int p=cnt[bb]; lpT[bb*NBLK+i]=p; cur[bb]=p; }
    __syncthreads();
    for(int k=tid;k<cc;k+=256){
      u32 s=(u32)esrc[e0+k], d=(u32)edst[e0+k];
      int p=atomicAdd(&cur[d>>7],1);
      stage[p] = s | ((d&127u)<<16);
    }
    __syncthreads();
    for(int k=tid;k<cc;k+=256) ebuf[(size_t)i*CH+k]=stage[k];   // coalesced
    return;
  }

  if(blockIdx.x == NBLK){
    // ---- W pre-stage: frag-major bf16 Wfg (32KB), done once ----
    // element W[k][nn] at u16 idx (((nn>>4)*4 + ks)*64 + q*16 + (nn&15))*8 + j
    const float4* W4 = (const float4*)W;
    for(int p=tid; p<2048; p+=256){
      int gg = p & 31, kk = p >> 5;
      int k0 = kk*2, n0 = gg*4;
      float4 w0 = W4[k0*32 + gg];
      float4 w1 = W4[(k0+1)*32 + gg];
      int ks = k0>>5, q = (k0>>3)&3, j = k0&7;   // j even
      float e0[4] = {w0.x,w0.y,w0.z,w0.w};
      float e1[4] = {w1.x,w1.y,w1.z,w1.w};
      #pragma unroll
      for(int u=0;u<4;u++){
        int nn = n0+u;
        int idx = (((nn>>4)*4 + ks)*64 + q*16 + (nn&15))*8 + j;
        ((u32*)Wfg)[idx>>1] = pack2(e0[u], e1[u]);
      }
    }
    return;
  }

  // ---- LN1 rows ----
  int row  = (int)(blockIdx.x - NBLK - 1)*4 + (tid>>6);
  int lane = tid & 63;
  if(row >= n) return;
  float2 xv = ((const float2*)(x + (size_t)row*128))[lane];
  float v0 = xv.x, v1 = xv.y;
  float mean = wsum(v0+v1) * (1.f/128.f);
  float d0 = v0-mean, d1 = v1-mean;
  float var = wsum(d0*d0 + d1*d1) * (1.f/128.f);
  float rstd = rsqrtf(var + EPS_LN);
  float2 gv = ((const float2*)g)[lane], bv = ((const float2*)b)[lane];
  float o0 = d0*rstd*gv.x + bv.x;
  float o1 = d1*rstd*gv.y + bv.y;
  ((u32*)(xt + (size_t)row*128))[lane] = pack2(o0, o1);
}

// ---------------- K2: binD' (blocks < NB) | MFMA GEMM (remaining blocks) ----------
__global__ __launch_bounds__(256) void gemmD_kernel(const u16* __restrict__ xt,
    const u16* __restrict__ Wfg, const float* __restrict__ att_src, const float* __restrict__ att_dst,
    u16* __restrict__ h, float* __restrict__ a_src, float* __restrict__ a_dst, int n,
    const u32* __restrict__ ebuf, const int* __restrict__ cntT, const int* __restrict__ lpT,
    int2* __restrict__ rowse, u16* __restrict__ col, int NB, int CH){
  __shared__ __align__(16) char smem[50176];   // gemm: Wf(32KB)+Xb(17KB); binD': ~19KB
  int tid = threadIdx.x;

  if(blockIdx.x < (u32)NB){
    // ---- binD': per-bucket sub-CSR (col segments padded to 4-u16 alignment) ----
    int bkt = blockIdx.x;
    int* segc = (int*)smem;                 // 256 ints @0
    int* dcnt = (int*)(smem+1024);          // 128 ints @1024 (raw counts, NOT scanned)
    int* dcur = (int*)(smem+1536);          // 128 ints @1536
    int* pst  = (int*)(smem+2048);          // 128 ints @2048 (padded starts, scanned)
    u32* list = (u32*)(smem+2560);          // CAP u32 @2560 (16KB)
    int c_i = cntT[bkt*NBLK+tid];           // this chunk's count for bucket bkt
    int l_i = lpT [bkt*NBLK+tid];           // local offset within chunk
    segc[tid] = c_i;
    if(tid<128) dcnt[tid]=0;
    __syncthreads();
    if(tid<64) wave_excl_scan(segc,256,tid);
    __syncthreads();
    int sb = segc[tid];
    int cb = segc[255] + cntT[bkt*NBLK+255];   // bucket total
    for(int k=0;k<c_i;k++) list[sb+k] = ebuf[(size_t)tid*CH + l_i + k];
    __syncthreads();
    for(int k=tid;k<cb;k+=256) atomicAdd(&dcnt[(list[k]>>16)&127], 1);
    __syncthreads();
    if(tid<128) pst[tid] = (dcnt[tid]+3)&~3;   // pad each segment to 4-u16 multiple
    __syncthreads();
    if(tid<64) wave_excl_scan(pst,128,tid);
    __syncthreads();
    int nd = min(128, n - (bkt<<7));
    if(tid<128){
      int st = pst[tid];
      dcur[tid] = st;
      if(tid<nd) rowse[(bkt<<7)+tid] = make_int2(bkt*CAP + st, dcnt[tid]);
    }
    __syncthreads();
    for(int k=tid;k<cb;k+=256){
      u32 v = list[k]; int l = (int)((v>>16)&127u);
      int p = atomicAdd(&dcur[l], 1);
      col[bkt*CAP + p] = (u16)(v & 0xffffu);
    }
    return;
  }

  // ---- GEMM tile: h = xt @ W (bf16) + attention logits ----
  u16* Wf = (u16*)smem;            // 16384 u16, frag-major W
  u16* Xb = (u16*)(smem+32768);    // 64*136 u16 tile; reused for h staging
  int r0 = (int)(blockIdx.x - NB)*64;
  // stage pre-converted W (plain copies: 2048 uint4, 8 per thread)
  {
    const uint4* Wg4 = (const uint4*)Wfg;
    uint4* Wf4 = (uint4*)Wf;
    for(int p=tid; p<2048; p+=256) Wf4[p] = Wg4[p];
  }
  for(int i=tid; i<1024; i+=256){
    int row = i>>4, seg = i&15;
    int gr = r0+row;
    uint4 v = (gr<n) ? ((const uint4*)(xt + (size_t)gr*128))[seg] : make_uint4(0,0,0,0);
    *(uint4*)&Xb[row*136 + seg*8] = v;
  }
  __syncthreads();

  int w = tid>>6, lane = tid&63;
  int slab = w*16, c = lane&15, q = lane>>4;
  f32x4 acc[8];
  #pragma unroll
  for(int t=0;t<8;t++) acc[t] = (f32x4){0.f,0.f,0.f,0.f};
  #pragma unroll
  for(int ks=0;ks<4;ks++){
    short8 A = *(const short8*)&Xb[(slab + c)*136 + ks*32 + q*8];
    #pragma unroll
    for(int t=0;t<8;t++){
      short8 B = *(const short8*)&Wf[((t*4+ks)*64 + lane)*8];
      acc[t] = __builtin_amdgcn_mfma_f32_16x16x32_bf16(A, B, acc[t], 0, 0, 0);
    }
  }
  __syncthreads();   // all waves done reading Xb
  #pragma unroll
  for(int t=0;t<8;t++){
    #pragma unroll
    for(int r=0;r<4;r++){
      Xb[(slab + q*4 + r)*136 + t*16 + c] = f2bf(acc[t][r]);   // C/D: col=lane&15, row=q*4+reg
    }
  }
  __syncthreads();
  {
    int row = tid>>2, qt = tid&3;
    int gr = r0+row;
    if(gr<n){
      const uint4* src = (const uint4*)((const char*)Xb + row*272 + qt*64);
      uint4* dst = (uint4*)((char*)(h + (size_t)gr*128) + qt*64);
      dst[0] = src[0];
      dst[1] = src[1];
      dst[2] = src[2];
      dst[3] = src[3];
    }
    int hd = qt;
    if(gr<n){
      float as=0.f, ad=0.f;
      const u16* hp = &Xb[row*136 + hd*32];
      #pragma unroll
      for(int sgm=0;sgm<4;sgm++){
        #pragma unroll
        for(int e=0;e<8;e++){
          float v = bf1(hp[sgm*8+e]);
          as = fmaf(v, att_src[hd*32+sgm*8+e], as);
          ad = fmaf(v, att_dst[hd*32+sgm*8+e], ad);
        }
      }
      a_src[(size_t)gr*4+hd] = as;
      a_dst[(size_t)gr*4+hd] = ad;
    }
  }
}

// ---------------- K3: Aggregation — softmax + gather + residual + LN2 -------------
// 16-lane group per dst, 4 dsts per wave, 3125 blocks. Lane li = 4*hc + eq owns
// channels li*8..li*8+7. y-pass: own head over 4 edges; col ids loaded as ONE
// guarded uint2 (segments 8B-aligned by binD' padding). Gather: ONE shfl/edge
// carrying packed (bf16(y)<<16 | sx). Denominator f32 (2 shfl_xor over eq bits).
// rowse[d] = (start, deg). No max-subtraction softmax (logits small; clamp 60).
__global__ __launch_bounds__(256) void agg_kernel(const u16* __restrict__ h,
    const float* __restrict__ a_src, const float* __restrict__ a_dst,
    const int2* __restrict__ rowse, const u16* __restrict__ col,
    const u16* __restrict__ xt, const float* __restrict__ bias,
    const float* __restrict__ g2, const float* __restrict__ b2,
    float* __restrict__ out, int n){
  int lane = threadIdx.x & 63;
  int wv   = threadIdx.x >> 6;
  int g    = lane >> 4;        // group within wave
  int li   = lane & 15;        // lane within group
  int hc   = li >> 2;          // head of this lane's 8 channels
  int eq   = li & 3;           // edge quad within chunk
  int gbase= g << 4;
  int d    = blockIdx.x*16 + wv*4 + g;
  bool dok = d < n;
  int dc   = dok ? d : (n-1);  // clamped: keep lanes alive for shfls

  float4 ad4v = ((const float4*)a_dst)[dc];
  float4 as4v = ((const float4*)a_src)[dc];
  float ad_h = hc==0? ad4v.x : hc==1? ad4v.y : hc==2? ad4v.z : ad4v.w;
  float as_h = hc==0? as4v.x : hc==1? as4v.y : hc==2? as4v.z : as4v.w;
  float t_h  = __expf(fminf(lrelu(as_h + ad_h), 60.f));   // self-loop term, own head

  int2 rs  = rowse[dc];
  int base = rs.x;             // multiple of 4 (padded starts)
  int deg  = dok ? rs.y : 0;
  int dm = deg;                       // wave-uniform max degree over 4 groups
  dm = max(dm, __shfl_xor(dm, 16, 64));
  dm = max(dm, __shfl_xor(dm, 32, 64));

  float psum = 0.f;
  float acc[8]={};
  for(int j0=0;j0<dm;j0+=16){
    // ---- y-pass: own head, 4 edges (4*eq+c); ONE uint2 col load ----
    int eb = j0 + eq*4;
    bool v0 = eb+0 < deg, v1 = eb+1 < deg, v2 = eb+2 < deg, v3 = eb+3 < deg;
    uint2 cv = make_uint2(0u,0u);
    if(eb < deg) cv = *(const uint2*)(col + base + eb);   // stays in padded segment
    int sx0 = (int)(cv.x & 0xffffu);
    int sx1 = (int)(cv.x >> 16);
    int sx2 = (int)(cv.y & 0xffffu);
    int sx3 = (int)(cv.y >> 16);
    float y0 = v0 ? __expf(fminf(lrelu(a_src[sx0*4+hc]+ad_h),60.f)) : 0.f;
    float y1 = v1 ? __expf(fminf(lrelu(a_src[sx1*4+hc]+ad_h),60.f)) : 0.f;
    float y2 = v2 ? __expf(fminf(lrelu(a_src[sx2*4+hc]+ad_h),60.f)) : 0.f;
    float y3 = v3 ? __expf(fminf(lrelu(a_src[sx3*4+hc]+ad_h),60.f)) : 0.f;
    psum += (y0+y1) + (y2+y3);
    int pk0 = (int)(((u32)f2bf(y0)<<16) | (u32)sx0);
    int pk1 = (int)(((u32)f2bf(y1)<<16) | (u32)sx1);
    int pk2 = (int)(((u32)f2bf(y2)<<16) | (u32)sx2);
    int pk3 = (int)(((u32)f2bf(y3)<<16) | (u32)sx3);
    // ---- gather: ONE shfl per edge (al=bfhi(v), sj=v&0xffff) ----
    int ccm = min(deg - j0, 16);
    #pragma unroll 1
    for(int a=0; a<4; a++){
      int jb = a*4;
      if(jb >= ccm) break;                 // group-uniform
      int srcl = gbase + hc*4 + a;
      #define AGG_STEP(cc, pv)                                                  \
        if(jb + cc < ccm){                                                      \
          u32 v = (u32)__shfl(pv, srcl, 64);                                    \
          float al = bfhi(v);                                                   \
          int   sj = (int)(v & 0xffffu);                                        \
          uint4 hv = *(const uint4*)(h + (size_t)sj*128 + li*8);                \
          acc[0]=fmaf(al,bflo(hv.x),acc[0]); acc[1]=fmaf(al,bfhi(hv.x),acc[1]); \
          acc[2]=fmaf(al,bflo(hv.y),acc[2]); acc[3]=fmaf(al,bfhi(hv.y),acc[3]); \
          acc[4]=fmaf(al,bflo(hv.z),acc[4]); acc[5]=fmaf(al,bfhi(hv.z),acc[5]); \
          acc[6]=fmaf(al,bflo(hv.w),acc[6]); acc[7]=fmaf(al,bfhi(hv.w),acc[7]); \
        }
      AGG_STEP(0, pk0)
      AGG_STEP(1, pk1)
      AGG_STEP(2, pk2)
      AGG_STEP(3, pk3)
      #undef AGG_STEP
    }
  }
  // denominator: reduce own-head partial across the 4 eq lanes of the quad
  psum += __shfl_xor(psum, 1, 64);
  psum += __shfl_xor(psum, 2, 64);
  float den = psum + t_h + EPS_SM;
  // self-loop message (each lane owns its channels)
  uint4 hd4 = *(const uint4*)(h + (size_t)dc*128 + li*8);
  acc[0]=fmaf(t_h,bflo(hd4.x),acc[0]); acc[1]=fmaf(t_h,bfhi(hd4.x),acc[1]);
  acc[2]=fmaf(t_h,bflo(hd4.y),acc[2]); acc[3]=fmaf(t_h,bfhi(hd4.y),acc[3]);
  acc[4]=fmaf(t_h,bflo(hd4.z),acc[4]); acc[5]=fmaf(t_h,bfhi(hd4.z),acc[5]);
  acc[6]=fmaf(t_h,bflo(hd4.w),acc[6]); acc[7]=fmaf(t_h,bfhi(hd4.w),acc[7]);
  float inv = 1.f/den;

  // bias + residual (bf16 xt) + LN2 (each channel once over 16 lanes -> /128)
  uint4 xv4 = *(const uint4*)(xt + (size_t)dc*128 + li*8);
  const float* bp = bias + li*8;
  float4 ba = *(const float4*)bp, bb = *(const float4*)(bp+4);
  float r[8];
  r[0]=bflo(xv4.x)+acc[0]*inv+ba.x; r[1]=bfhi(xv4.x)+acc[1]*inv+ba.y;
  r[2]=bflo(xv4.y)+acc[2]*inv+ba.z; r[3]=bfhi(xv4.y)+acc[3]*inv+ba.w;
  r[4]=bflo(xv4.z)+acc[4]*inv+bb.x; r[5]=bfhi(xv4.z)+acc[5]*inv+bb.y;
  r[6]=bflo(xv4.w)+acc[6]*inv+bb.z; r[7]=bfhi(xv4.w)+acc[7]*inv+bb.w;
  float part=0;
  #pragma unroll
  for(int c2=0;c2<8;c2++) part+=r[c2];
  #pragma unroll
  for(int o=1;o<16;o<<=1) part += __shfl_xor(part,o,64);
  float mean = part*(1.f/128.f);
  float vp=0;
  #pragma unroll
  for(int c2=0;c2<8;c2++){ float dd=r[c2]-mean; vp+=dd*dd; }
  #pragma unroll
  for(int o=1;o<16;o<<=1) vp += __shfl_xor(vp,o,64);
  float var = vp*(1.f/128.f);
  float rstd = rsqrtf(var+EPS_LN);
  const float* gp = g2 + li*8; const float* b2p = b2 + li*8;
  float4 ga = *(const float4*)gp,  gb = *(const float4*)(gp+4);
  float4 c2a= *(const float4*)b2p, c2b= *(const float4*)(b2p+4);
  if(dok){
    float* op = out + (size_t)d*128 + li*8;
    float4 o0 = make_float4((r[0]-mean)*rstd*ga.x+c2a.x, (r[1]-mean)*rstd*ga.y+c2a.y,
                            (r[2]-mean)*rstd*ga.z+c2a.z, (r[3]-mean)*rstd*ga.w+c2a.w);
    float4 o1 = make_float4((r[4]-mean)*rstd*gb.x+c2b.x, (r[5]-mean)*rstd*gb.y+c2b.y,
                            (r[6]-mean)*rstd*gb.z+c2b.z, (r[7]-mean)*rstd*gb.w+c2b.w);
    *(float4*)op     = o0;
    *(float4*)(op+4) = o1;
  }
}

extern "C" void kernel_launch(void* const* d_in, const int* in_sizes, int n_in,
                              void* d_out, int out_size, void* d_ws, size_t ws_size,
                              hipStream_t stream) {
  const float* x     = (const float*)d_in[0];
  const int*   ei    = (const int*)d_in[1];
  const float* W     = (const float*)d_in[4];
  const float* att_s = (const float*)d_in[5];
  const float* att_d = (const float*)d_in[6];
  const float* bias  = (const float*)d_in[7];
  const float* g1    = (const float*)d_in[8];
  const float* b1    = (const float*)d_in[9];
  const float* g2    = (const float*)d_in[10];
  const float* b2    = (const float*)d_in[11];
  int n = in_sizes[0]/128;
  int E = in_sizes[1]/2;
  float* out = (float*)d_out;

  int NB = (n+127)>>7;                 // 128-dst buckets (391 for n=50000)
  int CH = (E + NBLK - 1)/NBLK;        // edges per chunk (2344), <= CHMAX

  char* ws = (char*)d_ws;              // ~34 MB of 256 MiB used
  u16*   xt    = (u16*)ws;   ws += (size_t)n*128*2;
  u16*   h     = (u16*)ws;   ws += (size_t)n*128*2;
  float* a_src = (float*)ws; ws += (size_t)n*4*4;
  float* a_dst = (float*)ws; ws += (size_t)n*4*4;
  int2*  rowse = (int2*)ws;  ws += (size_t)n*8;
  u16*   col   = (u16*)ws;   ws += (size_t)NB*CAP*2;
  u32*   ebuf  = (u32*)ws;   ws += (size_t)NBLK*CH*4;
  int*   cntT  = (int*)ws;   ws += (size_t)NB*NBLK*4;
  int*   lpT   = (int*)ws;   ws += (size_t)NB*NBLK*4;
  u16*   Wfg   = (u16*)ws;   ws += 16384*2;   // frag-major bf16 W (32KB)

  int gemmTiles = (n+63)/64;
  dim3 b256(256);
  ln1C_kernel <<<NBLK + 1 + (n+3)/4, b256, 0, stream>>>(x, g1, b1, xt, n,
                                                        ei, ei+E, ebuf, cntT, lpT,
                                                        W, Wfg, E, CH, NB);
  gemmD_kernel<<<NB + gemmTiles,     b256, 0, stream>>>(xt, Wfg, att_s, att_d, h, a_src, a_dst, n,
                                                        ebuf, cntT, lpT, rowse, col, NB, CH);
  agg_kernel  <<<(n+15)/16,          b256, 0, stream>>>(h, a_src, a_dst, rowse, col,
                                                        xt, bias, g2, b2, out, n);
}